// Round 1
// baseline (161.438 us; speedup 1.0000x reference)
//
#include <hip/hip_runtime.h>

// B=64, T=128, D=512. gates = x @ w_ih^T per t; f-gate unused (c0=0).
// Kernel 1: bf16x3-split MFMA GEMM (i,g,o rows only) + fused LSTM activation -> h in d_out.
// Kernel 2: in-place softmax(20*h) over last dim.

#define B_ 64
#define T_ 128
#define D_ 512

typedef float f32x4_t __attribute__((ext_vector_type(4)));
typedef __bf16 bf16x8_t __attribute__((ext_vector_type(8)));
typedef unsigned short u16x8_t __attribute__((ext_vector_type(8)));

// Truncation split: f = hi + lo + O(2^-16 |f|). ~3 VALU/element.
__device__ __forceinline__ void cvt_hi_lo(float4 a, float4 b, u16x8_t& hi, u16x8_t& lo) {
  float f[8] = {a.x, a.y, a.z, a.w, b.x, b.y, b.z, b.w};
#pragma unroll
  for (int j = 0; j < 8; ++j) {
    unsigned u = __float_as_uint(f[j]);
    hi[j] = (unsigned short)(u >> 16);
    float fh = __uint_as_float(u & 0xffff0000u);
    float d = f[j] - fh;
    lo[j] = (unsigned short)(__float_as_uint(d) >> 16);
  }
}

__device__ __forceinline__ f32x4_t mfma_bf16(u16x8_t a, u16x8_t b, f32x4_t c) {
  return __builtin_amdgcn_mfma_f32_16x16x32_bf16(
      __builtin_bit_cast(bf16x8_t, a), __builtin_bit_cast(bf16x8_t, b), c, 0, 0, 0);
}

__device__ __forceinline__ float sigmoid_f(float v) { return 1.0f / (1.0f + __expf(-v)); }
__device__ __forceinline__ float tanh_f(float v) { return 1.0f - 2.0f / (__expf(2.0f * v) + 1.0f); }

// Grid: 1024 WGs = 128 t x 8 d-tiles (DT=64). Block: 256 threads = 4 waves.
// Wave wv owns output cols [d0 + wv*16, d0 + wv*16 + 16) for all 64 batch rows,
// accumulating i/g/o gate tiles simultaneously (same C-fragment coords).
__global__ __launch_bounds__(256, 2) void lstm_gates_kernel(
    const float* __restrict__ x, const float* __restrict__ w, float* __restrict__ hout) {
  const int lane = threadIdx.x & 63;
  const int wv = threadIdx.x >> 6;
  const int bid = blockIdx.x;
  // XCD swizzle: all 8 d-tiles of one t land on the same XCD -> x[t] is L2-resident.
  const int work = (bid & 7) * 128 + (bid >> 3);
  const int t = work >> 3;
  const int d0 = (work & 7) << 6;

  const int r = lane & 15;   // A-row / B-col within 16x16 tile
  const int kg = lane >> 4;  // k-subgroup: elems kg*8 .. kg*8+7

  // x[b][t][d]: b = mt*16 + r, addr = ((b*T + t)*D + k + kg*8)
  const float* xb[4];
#pragma unroll
  for (int mt = 0; mt < 4; ++mt)
    xb[mt] = x + (((size_t)(mt * 16 + r) * T_ + t) << 9) + kg * 8;

  // w[t][row][d]: rows for gates i (0), g (2D), o (3D); f skipped entirely.
  const int gbase[3] = {0, 2 * D_, 3 * D_};
  const float* wb[3];
#pragma unroll
  for (int g = 0; g < 3; ++g)
    wb[g] = w + ((size_t)t << 20) + ((size_t)(gbase[g] + d0 + wv * 16 + r) << 9) + kg * 8;

  f32x4_t acc[4][3];
#pragma unroll
  for (int mt = 0; mt < 4; ++mt)
#pragma unroll
    for (int g = 0; g < 3; ++g)
      acc[mt][g] = (f32x4_t){0.f, 0.f, 0.f, 0.f};

#pragma unroll 2
  for (int k = 0; k < D_; k += 32) {
    u16x8_t xhi[4], xlo[4], whi[3], wlo[3];
#pragma unroll
    for (int mt = 0; mt < 4; ++mt) {
      float4 a = *(const float4*)(xb[mt] + k);
      float4 b = *(const float4*)(xb[mt] + k + 4);
      cvt_hi_lo(a, b, xhi[mt], xlo[mt]);
    }
#pragma unroll
    for (int g = 0; g < 3; ++g) {
      float4 a = *(const float4*)(wb[g] + k);
      float4 b = *(const float4*)(wb[g] + k + 4);
      cvt_hi_lo(a, b, whi[g], wlo[g]);
    }
#pragma unroll
    for (int mt = 0; mt < 4; ++mt)
#pragma unroll
      for (int g = 0; g < 3; ++g) {
        acc[mt][g] = mfma_bf16(xhi[mt], whi[g], acc[mt][g]);  // hi*hi
        acc[mt][g] = mfma_bf16(xhi[mt], wlo[g], acc[mt][g]);  // hi*lo
        acc[mt][g] = mfma_bf16(xlo[mt], whi[g], acc[mt][g]);  // lo*hi
      }
  }

  // C layout: col = lane&15, row = (lane>>4)*4 + j  [m89-verified]
  const int dcol = d0 + wv * 16 + r;
#pragma unroll
  for (int mt = 0; mt < 4; ++mt) {
#pragma unroll
    for (int j = 0; j < 4; ++j) {
      float iv = acc[mt][0][j];
      float gv = acc[mt][1][j];
      float ov = acc[mt][2][j];
      float c = sigmoid_f(iv) * tanh_f(gv);
      float h = sigmoid_f(ov) * tanh_f(c);
      int b = mt * 16 + kg * 4 + j;
      hout[(((size_t)b * T_ + t) << 9) + dcol] = h;
    }
  }
}

// One wave per (b,t) row of 512; in-place softmax(20*h).
__global__ __launch_bounds__(256) void softmax_kernel(float* __restrict__ io) {
  const int lane = threadIdx.x & 63;
  const int row = blockIdx.x * 4 + (threadIdx.x >> 6);
  float* p = io + ((size_t)row << 9);
  float4 v0 = *(const float4*)(p + lane * 4);
  float4 v1 = *(const float4*)(p + 256 + lane * 4);
  float l[8] = {20.f * v0.x, 20.f * v0.y, 20.f * v0.z, 20.f * v0.w,
                20.f * v1.x, 20.f * v1.y, 20.f * v1.z, 20.f * v1.w};
  float m = l[0];
#pragma unroll
  for (int j = 1; j < 8; ++j) m = fmaxf(m, l[j]);
#pragma unroll
  for (int o = 32; o > 0; o >>= 1) m = fmaxf(m, __shfl_xor(m, o, 64));
  float e[8], s = 0.f;
#pragma unroll
  for (int j = 0; j < 8; ++j) {
    e[j] = __expf(l[j] - m);
    s += e[j];
  }
#pragma unroll
  for (int o = 32; o > 0; o >>= 1) s += __shfl_xor(s, o, 64);
  float inv = 1.0f / s;
  float4 o0 = {e[0] * inv, e[1] * inv, e[2] * inv, e[3] * inv};
  float4 o1 = {e[4] * inv, e[5] * inv, e[6] * inv, e[7] * inv};
  *(float4*)(p + lane * 4) = o0;
  *(float4*)(p + 256 + lane * 4) = o1;
}

extern "C" void kernel_launch(void* const* d_in, const int* in_sizes, int n_in,
                              void* d_out, int out_size, void* d_ws, size_t ws_size,
                              hipStream_t stream) {
  const float* x = (const float*)d_in[0];
  const float* w = (const float*)d_in[1];
  float* out = (float*)d_out;
  lstm_gates_kernel<<<T_ * 8, 256, 0, stream>>>(x, w, out);
  softmax_kernel<<<(B_ * T_) / 4, 256, 0, stream>>>(out);
}

// Round 2
// 149.882 us; speedup vs baseline: 1.0771x; 1.0771x over previous
//
#include <hip/hip_runtime.h>

// B=64, T=128, D=512. gates = x @ w_ih^T per t; f-gate unused (c0=0).
// Kernel 0: split x (fp32) -> interleaved bf16 hi/lo groups in d_ws.
// Kernel 1: bf16x3-split MFMA GEMM (i,g,o rows only) + fused LSTM activation -> h.
// Kernel 2: in-place softmax(20*h).

#define B_ 64
#define T_ 128
#define D_ 512

typedef float f32x4_t __attribute__((ext_vector_type(4)));
typedef __bf16 bf16x8_t __attribute__((ext_vector_type(8)));
typedef unsigned short u16x8_t __attribute__((ext_vector_type(8)));

// Truncation split: f = hi + lo + O(2^-16 |f|).
__device__ __forceinline__ void cvt_hi_lo(float4 a, float4 b, u16x8_t& hi, u16x8_t& lo) {
  float f[8] = {a.x, a.y, a.z, a.w, b.x, b.y, b.z, b.w};
#pragma unroll
  for (int j = 0; j < 8; ++j) {
    unsigned u = __float_as_uint(f[j]);
    hi[j] = (unsigned short)(u >> 16);
    float fh = __uint_as_float(u & 0xffff0000u);
    float d = f[j] - fh;
    lo[j] = (unsigned short)(__float_as_uint(d) >> 16);
  }
}

__device__ __forceinline__ f32x4_t mfma_bf16(u16x8_t a, u16x8_t b, f32x4_t c) {
  return __builtin_amdgcn_mfma_f32_16x16x32_bf16(
      __builtin_bit_cast(bf16x8_t, a), __builtin_bit_cast(bf16x8_t, b), c, 0, 0, 0);
}

__device__ __forceinline__ float sigmoid_f(float v) { return 1.0f / (1.0f + __expf(-v)); }
__device__ __forceinline__ float tanh_f(float v) { return 1.0f - 2.0f / (__expf(2.0f * v) + 1.0f); }

// Kernel 0: each thread converts one 8-elem group. ws layout: per group j,
// ushorts [j*16, j*16+8) = hi, [j*16+8, j*16+16) = lo. 524288 groups total.
__global__ __launch_bounds__(256) void split_x_kernel(const float* __restrict__ x,
                                                      unsigned short* __restrict__ ws) {
  const int j = blockIdx.x * 256 + threadIdx.x;
  float4 a = *(const float4*)(x + (size_t)j * 8);
  float4 b = *(const float4*)(x + (size_t)j * 8 + 4);
  u16x8_t hi, lo;
  cvt_hi_lo(a, b, hi, lo);
  *(u16x8_t*)(ws + (size_t)j * 16) = hi;
  *(u16x8_t*)(ws + (size_t)j * 16 + 8) = lo;
}

// Grid: 1024 WGs = 128 t x 8 d-tiles (DT=64). Block: 256 threads = 4 waves,
// forced to 4 blocks/CU (all 1024 resident, 16 waves/CU) for memory-level parallelism.
__global__ __launch_bounds__(256, 4) void lstm_gates_kernel(
    const unsigned short* __restrict__ xs, const float* __restrict__ w,
    float* __restrict__ hout) {
  const int lane = threadIdx.x & 63;
  const int wv = threadIdx.x >> 6;
  const int bid = blockIdx.x;
  // XCD swizzle: all 8 d-tiles of one t land on the same XCD -> x[t] L2-resident.
  const int work = (bid & 7) * 128 + (bid >> 3);
  const int t = work >> 3;
  const int d0 = (work & 7) << 6;

  const int r = lane & 15;   // A-row / B-col within 16x16 tile
  const int kg = lane >> 4;  // k-subgroup: elems kg*8 .. kg*8+7

  // x groups: (b*T + t)*64 groups of 16 ushorts; lane needs group k/8+kg.
  const unsigned short* xp[4];
#pragma unroll
  for (int mt = 0; mt < 4; ++mt)
    xp[mt] = xs + ((size_t)((mt * 16 + r) * T_ + t) << 10) + kg * 16;

  // w[t][row][d]: rows for gates i (0), g (2D), o (3D); f skipped entirely.
  const float* wp[3];
  const int gbase[3] = {0, 2 * D_, 3 * D_};
#pragma unroll
  for (int g = 0; g < 3; ++g)
    wp[g] = w + ((size_t)t << 20) + ((size_t)(gbase[g] + d0 + wv * 16 + r) << 9) + kg * 8;

  f32x4_t acc[4][3];
#pragma unroll
  for (int mt = 0; mt < 4; ++mt)
#pragma unroll
    for (int g = 0; g < 3; ++g)
      acc[mt][g] = (f32x4_t){0.f, 0.f, 0.f, 0.f};

  for (int k = 0; k < D_; k += 32) {
    u16x8_t xh[4], xl[4];
#pragma unroll
    for (int mt = 0; mt < 4; ++mt) {
      xh[mt] = *(const u16x8_t*)(xp[mt] + k * 2);
      xl[mt] = *(const u16x8_t*)(xp[mt] + k * 2 + 8);
    }
#pragma unroll
    for (int g = 0; g < 3; ++g) {
      float4 a = *(const float4*)(wp[g] + k);
      float4 b = *(const float4*)(wp[g] + k + 4);
      u16x8_t wh, wl;
      cvt_hi_lo(a, b, wh, wl);
#pragma unroll
      for (int mt = 0; mt < 4; ++mt) {
        acc[mt][g] = mfma_bf16(xh[mt], wh, acc[mt][g]);  // hi*hi
        acc[mt][g] = mfma_bf16(xh[mt], wl, acc[mt][g]);  // hi*lo
        acc[mt][g] = mfma_bf16(xl[mt], wh, acc[mt][g]);  // lo*hi
      }
    }
  }

  // C layout: col = lane&15, row = (lane>>4)*4 + j  [m89-verified]
  const int dcol = d0 + wv * 16 + r;
#pragma unroll
  for (int mt = 0; mt < 4; ++mt) {
#pragma unroll
    for (int j = 0; j < 4; ++j) {
      float iv = acc[mt][0][j];
      float gv = acc[mt][1][j];
      float ov = acc[mt][2][j];
      float c = sigmoid_f(iv) * tanh_f(gv);
      float h = sigmoid_f(ov) * tanh_f(c);
      int b = mt * 16 + kg * 4 + j;
      hout[(((size_t)b * T_ + t) << 9) + dcol] = h;
    }
  }
}

// One wave per (b,t) row of 512; in-place softmax(20*h).
__global__ __launch_bounds__(256) void softmax_kernel(float* __restrict__ io) {
  const int lane = threadIdx.x & 63;
  const int row = blockIdx.x * 4 + (threadIdx.x >> 6);
  float* p = io + ((size_t)row << 9);
  float4 v0 = *(const float4*)(p + lane * 4);
  float4 v1 = *(const float4*)(p + 256 + lane * 4);
  float l[8] = {20.f * v0.x, 20.f * v0.y, 20.f * v0.z, 20.f * v0.w,
                20.f * v1.x, 20.f * v1.y, 20.f * v1.z, 20.f * v1.w};
  float m = l[0];
#pragma unroll
  for (int j = 1; j < 8; ++j) m = fmaxf(m, l[j]);
#pragma unroll
  for (int o = 32; o > 0; o >>= 1) m = fmaxf(m, __shfl_xor(m, o, 64));
  float e[8], s = 0.f;
#pragma unroll
  for (int j = 0; j < 8; ++j) {
    e[j] = __expf(l[j] - m);
    s += e[j];
  }
#pragma unroll
  for (int o = 32; o > 0; o >>= 1) s += __shfl_xor(s, o, 64);
  float inv = 1.0f / s;
  float4 o0 = {e[0] * inv, e[1] * inv, e[2] * inv, e[3] * inv};
  float4 o1 = {e[4] * inv, e[5] * inv, e[6] * inv, e[7] * inv};
  *(float4*)(p + lane * 4) = o0;
  *(float4*)(p + 256 + lane * 4) = o1;
}

extern "C" void kernel_launch(void* const* d_in, const int* in_sizes, int n_in,
                              void* d_out, int out_size, void* d_ws, size_t ws_size,
                              hipStream_t stream) {
  const float* x = (const float*)d_in[0];
  const float* w = (const float*)d_in[1];
  float* out = (float*)d_out;
  unsigned short* xs = (unsigned short*)d_ws;  // 16.8 MB of bf16 hi/lo groups

  split_x_kernel<<<(B_ * T_ * D_) / (256 * 8), 256, 0, stream>>>(x, xs);
  lstm_gates_kernel<<<T_ * 8, 256, 0, stream>>>(xs, w, out);
  softmax_kernel<<<(B_ * T_) / 4, 256, 0, stream>>>(out);
}